// Round 14
// baseline (691.895 us; speedup 1.0000x reference)
//
#include <hip/hip_runtime.h>

// SOHMM forward, MI355X gfx950 — round 14: R12 protocol, b-split geometry, 1 barrier/step.
// 256 blocks = (j x b-half of 32) x 512 threads (8 waves).
//  - y words in d_out carry tag 2s+1 in the f32 low byte (deterministic rounding);
//    consumers poll y directly (the per-step all-to-all transpose: column j reads row j).
//  - Stabilizer: per-(j,b) row max of the polled row (R12-proven numerics), computed
//    IN-WAVE via shfl_xor (wave w polls b in {4w..4w+3}) -> no LDS reduce barrier.
//  - Ping-pong ET buffers -> single __syncthreads per step.
//  - Final y_final rendezvous (global per-b max + partial sums) via tagged mslot/fpart
//    sweeps in d_ws (memset-rearmed every launch/replay).

#define Hd 128
#define Bd 64
#define Sd 128
#define Vd 32000
#define HBc (Hd * Bd)          // 8192
#define HHBc (Hd * Hd * Bd)    // 1048576
#define NBLK 256
#define NTHR 512
#define EPSF 1e-12f
#define FTAG 200u

typedef __attribute__((ext_vector_type(4))) float f32x4;
typedef __attribute__((ext_vector_type(8))) short s16x8;
typedef __attribute__((ext_vector_type(4))) short s16x4;

__device__ __forceinline__ short f2bf(float f) {
  unsigned u = __builtin_bit_cast(unsigned, f);
  unsigned r = (u + 0x7fffu + ((u >> 16) & 1u)) >> 16;
  return (short)(r & 0xffffu);
}
__device__ __forceinline__ unsigned mono_enc(float f) {
  unsigned u = __builtin_bit_cast(unsigned, f);
  return u ^ ((u & 0x80000000u) ? 0xFFFFFFFFu : 0x80000000u);
}
__device__ __forceinline__ float mono_dec(unsigned m) {
  unsigned u = (m & 0x80000000u) ? (m ^ 0x80000000u) : ~m;
  return __builtin_bit_cast(float, u);
}
__device__ __forceinline__ unsigned packM(float f, unsigned tag) {
  return (tag << 24) | (mono_enc(f) >> 8);
}
__device__ __forceinline__ float decM(unsigned w) {
  return mono_dec((w & 0x00FFFFFFu) << 8);
}
__device__ __forceinline__ unsigned pack_y(float v, unsigned tag) {
  unsigned u = __builtin_bit_cast(unsigned, v);
  return ((u + 0x80u) & 0xFFFFFF00u) | tag;
}
__device__ __forceinline__ float as_f(unsigned u) { return __builtin_bit_cast(float, u); }
__device__ __forceinline__ unsigned pack24(float f, unsigned tag) {
  unsigned u = __builtin_bit_cast(unsigned, f);
  return ((u + 0x80u) & 0xFFFFFF00u) | tag;
}
__device__ __forceinline__ float dec24(unsigned v) {
  return __builtin_bit_cast(float, v & 0xFFFFFF00u);
}

// LLC-coherent accessors (agent scope -> sc1 both directions).
__device__ __forceinline__ unsigned ld_u32(const unsigned* p) {
  return __hip_atomic_load(p, __ATOMIC_RELAXED, __HIP_MEMORY_SCOPE_AGENT);
}
__device__ __forceinline__ void st_u32(unsigned* p, unsigned v) {
  __hip_atomic_store(p, v, __ATOMIC_RELAXED, __HIP_MEMORY_SCOPE_AGENT);
}

__global__ __launch_bounds__(NTHR) void sohmm_persistent(
    const int* __restrict__ ids, const float* __restrict__ alpha,
    const float* __restrict__ beta, const float* __restrict__ gamma,
    float* __restrict__ out, unsigned* __restrict__ mslot,
    unsigned* __restrict__ fpart) {
  const int tid = threadIdx.x;
  const int bid = blockIdx.x;
  const int j = bid >> 1;        // column
  const int h = bid & 1;         // b-half
  const int lane = tid & 63;
  const int w = tid >> 6;        // wave 0..7
  const int l15 = lane & 15;
  const int g4 = lane >> 4;
  // poll mapping: wave w handles local b in {4w..4w+3}
  const int pb = w * 4 + (lane & 3);   // local b this lane polls/stages
  const int kg = lane >> 2;            // k-group 0..15
  const int k0 = kg * 8;
  // MFMA mapping: wave w = i-tile w; two b-tiles
  const int i0 = w * 16;
  const int bl0 = l15;           // local b, tile 0
  const int bl1 = 16 + l15;      // local b, tile 1

  __shared__ __align__(16) short ET[2][32][132];  // ping-pong E^T[b][k] bf16
  __shared__ float MbL[2][32];                    // ping-pong row-max per local b
  __shared__ __align__(16) float ipl[Sd][32];     // beta[j, ids[b, S-1-t]], this half
  __shared__ float gex[128];
  __shared__ float gred[2][8];
  __shared__ float wredA[8][32];
  __shared__ unsigned redSu[16][32];
  __shared__ float redF2[8][64];
  __shared__ unsigned redM2[8][64];

  // ---- A fragments: alpha[i, j, :], i-tile w ----
  s16x8 afrag[4];
  {
    const int i = i0 + l15;
    const float* ap = alpha + ((size_t)i * Hd + j) * Hd;
#pragma unroll
    for (int kc = 0; kc < 4; ++kc) {
      const int k = kc * 32 + g4 * 8;
      f32x4 a0 = *(const f32x4*)(ap + k);
      f32x4 a1 = *(const f32x4*)(ap + k + 4);
      s16x8 f;
      f[0] = f2bf(a0[0]); f[1] = f2bf(a0[1]); f[2] = f2bf(a0[2]); f[3] = f2bf(a0[3]);
      f[4] = f2bf(a1[0]); f[5] = f2bf(a1[1]); f[6] = f2bf(a1[2]); f[7] = f2bf(a1[3]);
      afrag[kc] = f;
    }
  }

  // ---- phase 0: ip table (this half), gamma stats, tagged y0 ----
  for (int idx = tid; idx < Sd * 32; idx += NTHR) {
    const int t = idx >> 5, bq = idx & 31;
    ipl[t][bq] = beta[(size_t)j * Vd + ids[(h * 32 + bq) * Sd + (Sd - 1 - t)]];
  }
  {
    float m = -3.4e38f;
#pragma unroll
    for (int c = 0; c < 8; ++c) {
      f32x4 g = *(const f32x4*)(gamma + (size_t)(c * NTHR + tid) * 4);
      m = fmaxf(fmaxf(fmaxf(m, g[0]), g[1]), fmaxf(g[2], g[3]));
    }
#pragma unroll
    for (int o = 32; o >= 1; o >>= 1) m = fmaxf(m, __shfl_xor(m, o, 64));
    if (lane == 0) gred[0][w] = m;
  }
  __syncthreads();  // ipl + gamma max partials ready
  {
    // tagged y0 stores (tag 1): 128 i-rows x this half's 32 b
    const int i = tid >> 2;
    const int b8 = (tid & 3) * 8;
    unsigned* yw = (unsigned*)out + ((size_t)i * Hd + j) * Bd + h * 32 + b8;
#pragma unroll
    for (int e = 0; e < 8; ++e) st_u32(yw + e, pack_y(ipl[0][b8 + e], 1u));
  }
  {
    float gm = gred[0][0];
#pragma unroll
    for (int q = 1; q < 8; ++q) gm = fmaxf(gm, gred[0][q]);
    float ss = 0.f;
#pragma unroll
    for (int c = 0; c < 8; ++c) {
      f32x4 g = *(const f32x4*)(gamma + (size_t)(c * NTHR + tid) * 4);
      ss += __expf(g[0] - gm) + __expf(g[1] - gm) + __expf(g[2] - gm) + __expf(g[3] - gm);
    }
#pragma unroll
    for (int o = 32; o >= 1; o >>= 1) ss += __shfl_xor(ss, o, 64);
    if (lane == 0) gred[1][w] = ss;
    __syncthreads();
    float gs = 0.f;
#pragma unroll
    for (int q = 0; q < 8; ++q) gs += gred[1][q];
    if (tid < 128) gex[tid] = __expf(gamma[(size_t)tid * Hd + j] - gm) * (1.f / gs);
  }
  __syncthreads();

  // ---- main scan: s = 1 .. 127 — one barrier per step ----
  float val0[4], val1[4];
  int p = 0;
#pragma unroll 1
  for (int s = 1; s < Sd; ++s) {
    const unsigned ytag = (unsigned)(2 * s - 1);
    const unsigned wtag = (unsigned)(2 * s + 1);

    // 1) poll 8 y_{s-1} words for (k = k0.., b = pb)
    const unsigned* ypw = (const unsigned*)out + (size_t)(s - 1) * HHBc +
                          (size_t)j * HBc + h * 32 + pb;
    unsigned g[8];
#pragma unroll
    for (int e = 0; e < 8; ++e) g[e] = ld_u32(ypw + (size_t)(k0 + e) * Bd);
    {
      unsigned spins = 0;
      for (;;) {
        unsigned bad = 0;
#pragma unroll
        for (int e = 0; e < 8; ++e) bad |= (g[e] & 0xFFu) ^ ytag;
        if (!bad) break;
        if (++spins > (1u << 18)) break;
        __builtin_amdgcn_s_sleep(1);
#pragma unroll
        for (int e = 0; e < 8; ++e)
          if ((g[e] & 0xFFu) != ytag) g[e] = ld_u32(ypw + (size_t)(k0 + e) * Bd);
      }
    }

    // 2) in-wave row max for b = pb (16 lanes share pb: masks 4,8,16,32)
    float pm = as_f(g[0]);
#pragma unroll
    for (int e = 1; e < 8; ++e) pm = fmaxf(pm, as_f(g[e]));
    pm = fmaxf(pm, __shfl_xor(pm, 4, 64));
    pm = fmaxf(pm, __shfl_xor(pm, 8, 64));
    pm = fmaxf(pm, __shfl_xor(pm, 16, 64));
    pm = fmaxf(pm, __shfl_xor(pm, 32, 64));

    // 3) stage E^T = bf16(exp(y - rowmax)), args <= 0
    {
      s16x8 uv;
#pragma unroll
      for (int e = 0; e < 8; ++e) ((short*)&uv)[e] = f2bf(__expf(as_f(g[e]) - pm));
      *(s16x8*)&ET[p][pb][k0] = uv;
      if (kg == 0) MbL[p][pb] = pm;
    }
    __syncthreads();  // the one barrier: ET[p] + MbL[p] ready

    // 4) MFMA: i-tile w, b-tiles 0 and 1
    f32x4 acc0 = (f32x4){0.f, 0.f, 0.f, 0.f};
    f32x4 acc1 = (f32x4){0.f, 0.f, 0.f, 0.f};
#pragma unroll
    for (int kc = 0; kc < 4; ++kc) {
      const int kk = kc * 32 + g4 * 8;
      union { s16x4 hh[2]; s16x8 v; } u0, u1;
      u0.hh[0] = *(const s16x4*)&ET[p][bl0][kk];
      u0.hh[1] = *(const s16x4*)&ET[p][bl0][kk + 4];
      u1.hh[0] = *(const s16x4*)&ET[p][bl1][kk];
      u1.hh[1] = *(const s16x4*)&ET[p][bl1][kk + 4];
      acc0 = __builtin_amdgcn_mfma_f32_16x16x32_bf16(afrag[kc], u0.v, acc0, 0, 0, 0);
      acc1 = __builtin_amdgcn_mfma_f32_16x16x32_bf16(afrag[kc], u1.v, acc1, 0, 0, 0);
    }

    // 5) epilogue: val = log(acc+eps) + M + ip ; tagged y stores
    {
      const float add0 = MbL[p][bl0] + ipl[s][bl0];
      const float add1 = MbL[p][bl1] + ipl[s][bl1];
      unsigned* ycw = (unsigned*)out + (size_t)s * HHBc;
#pragma unroll
      for (int r = 0; r < 4; ++r) {
        const size_t row = (size_t)(i0 + g4 * 4 + r) * HBc + (size_t)j * Bd + h * 32;
        const float v0 = __logf(acc0[r] + EPSF) + add0;
        const float v1 = __logf(acc1[r] + EPSF) + add1;
        val0[r] = v0; val1[r] = v1;
        st_u32(ycw + row + bl0, pack_y(v0, wtag));
        st_u32(ycw + row + bl1, pack_y(v1, wtag));
      }
    }
    p ^= 1;  // next step writes the other ET/MbL buffer (no post-MFMA barrier needed)
  }

  // ---- final rendezvous: global per-b max (this half) + partial sums + y_final ----
  {
    float m0 = fmaxf(fmaxf(val0[0], val0[1]), fmaxf(val0[2], val0[3]));
    m0 = fmaxf(m0, __shfl_xor(m0, 16, 64));
    m0 = fmaxf(m0, __shfl_xor(m0, 32, 64));
    float m1 = fmaxf(fmaxf(val1[0], val1[1]), fmaxf(val1[2], val1[3]));
    m1 = fmaxf(m1, __shfl_xor(m1, 16, 64));
    m1 = fmaxf(m1, __shfl_xor(m1, 32, 64));
    if (lane < 16) { wredA[w][lane] = m0; wredA[w][16 + lane] = m1; }
  }
  __syncthreads();
  if (tid < 32) {
    float mm = wredA[0][tid];
#pragma unroll
    for (int q = 1; q < 8; ++q) mm = fmaxf(mm, wredA[q][tid]);
    st_u32(mslot + (size_t)j * Bd + h * 32 + tid, packM(mm, 1u));
  }
  // sweep Mg for this half's 32 b over 128 j-producers (8 per thread)
  {
    const int b = tid & 31, jq = tid >> 5;   // 16 groups x 8 producers
    const unsigned* pm = mslot + (size_t)(jq * 8) * Bd + h * 32 + b;
    unsigned gg[8];
#pragma unroll
    for (int q = 0; q < 8; ++q) gg[q] = ld_u32(pm + (size_t)q * Bd);
    unsigned spins = 0;
    for (;;) {
      unsigned bad = 0;
#pragma unroll
      for (int q = 0; q < 8; ++q) bad |= (gg[q] >> 24) ^ 1u;
      if (!bad) break;
      if (++spins > (1u << 18)) break;
      __builtin_amdgcn_s_sleep(1);
#pragma unroll
      for (int q = 0; q < 8; ++q)
        if ((gg[q] >> 24) != 1u) gg[q] = ld_u32(pm + (size_t)q * Bd);
    }
    unsigned mx = 0u;
#pragma unroll
    for (int q = 0; q < 8; ++q) mx = gg[q] > mx ? gg[q] : mx;
    redSu[jq][b] = mx;
  }
  __syncthreads();
  // partial sums with the consistent Mg
  {
    unsigned mg0 = redSu[0][bl0], mg1 = redSu[0][bl1];
#pragma unroll
    for (int q = 1; q < 16; ++q) {
      mg0 = redSu[q][bl0] > mg0 ? redSu[q][bl0] : mg0;
      mg1 = redSu[q][bl1] > mg1 ? redSu[q][bl1] : mg1;
    }
    const float Mg0 = decM(mg0), Mg1 = decM(mg1);
    float s0 = 0.f, s1 = 0.f;
#pragma unroll
    for (int r = 0; r < 4; ++r) {
      const float gx = gex[i0 + g4 * 4 + r];
      s0 += gx * __expf(val0[r] - Mg0);
      s1 += gx * __expf(val1[r] - Mg1);
    }
    s0 += __shfl_xor(s0, 16, 64); s0 += __shfl_xor(s0, 32, 64);
    s1 += __shfl_xor(s1, 16, 64); s1 += __shfl_xor(s1, 32, 64);
    if (lane < 16) { wredA[w][lane] = s0; wredA[w][16 + lane] = s1; }
  }
  __syncthreads();
  if (tid < 32) {
    float tot = wredA[0][tid];
#pragma unroll
    for (int q = 1; q < 8; ++q) tot += wredA[q][tid];
    st_u32(fpart + (size_t)j * Bd + h * 32 + tid, pack24(tot, FTAG));
  }

  if (bid == 0) {
    // gather all 128 j-producers' sums and maxes for all 64 b
    const int b = tid & 63, jq = tid >> 6;   // 8 groups x 16 producers
    const unsigned* pf = fpart + (size_t)(jq * 16) * Bd + b;
    const unsigned* pmm = mslot + (size_t)(jq * 16) * Bd + b;
    unsigned gf[16], gm[16];
#pragma unroll
    for (int q = 0; q < 16; ++q) { gf[q] = ld_u32(pf + (size_t)q * Bd); gm[q] = ld_u32(pmm + (size_t)q * Bd); }
    {
      unsigned spins = 0;
      for (;;) {
        unsigned bad = 0;
#pragma unroll
        for (int q = 0; q < 16; ++q) {
          bad |= (gf[q] & 0xFFu) ^ FTAG;
          bad |= (gm[q] >> 24) ^ 1u;
        }
        if (!bad) break;
        if (++spins > (1u << 18)) break;
        __builtin_amdgcn_s_sleep(1);
#pragma unroll
        for (int q = 0; q < 16; ++q) {
          if ((gf[q] & 0xFFu) != FTAG) gf[q] = ld_u32(pf + (size_t)q * Bd);
          if ((gm[q] >> 24) != 1u) gm[q] = ld_u32(pmm + (size_t)q * Bd);
        }
      }
    }
    float sf = 0.f;
    unsigned mx = 0u;
#pragma unroll
    for (int q = 0; q < 16; ++q) {
      sf += dec24(gf[q]);
      mx = gm[q] > mx ? gm[q] : mx;
    }
    redF2[jq][b] = sf;
    redM2[jq][b] = mx;
    __syncthreads();
    if (tid < 64) {
      float tot = 0.f;
      unsigned mg = 0u;
#pragma unroll
      for (int q = 0; q < 8; ++q) {
        tot += redF2[q][tid];
        mg = redM2[q][tid] > mg ? redM2[q][tid] : mg;
      }
      out[(size_t)Sd * HHBc + tid] = __logf(tot + EPSF) + decM(mg);
    }
  }
}

extern "C" void kernel_launch(void* const* d_in, const int* in_sizes, int n_in,
                              void* d_out, int out_size, void* d_ws, size_t ws_size,
                              hipStream_t stream) {
  const int* ids = (const int*)d_in[0];
  const float* alpha = (const float*)d_in[1];
  const float* beta = (const float*)d_in[2];
  const float* gamma = (const float*)d_in[3];
  float* out = (float*)d_out;
  unsigned* mslot = (unsigned*)d_ws;               // [128][64] u32 = 32 KB (final Mg)
  unsigned* fpart = mslot + 128 * Bd;              // [128][64] u32 = 32 KB

  // Re-arm the final-rendezvous gates every launch (graph node, re-runs each replay).
  hipMemsetAsync(mslot, 0, 2 * 128 * Bd * sizeof(unsigned), stream);
  hipLaunchKernelGGL(sohmm_persistent, dim3(NBLK), dim3(NTHR), 0, stream,
                     ids, alpha, beta, gamma, out, mslot, fpart);
}